// Round 12
// baseline (647.900 us; speedup 1.0000x reference)
//
#include <hip/hip_runtime.h>
#include <math.h>

// GAT 3-layer: N=50000 nodes, E=800000 edges (+N self loops), HEADS=2, HID=64.
// R12: sliced gather v3. Evidence: R8-R11 aggregate invariant at ~61us /
// 194MB FETCH / 3.3TB/s despite 2x MLP -> bound by L2-miss service rate on
// random 512B rows; only fewer miss bytes help. Slicing (verified 194->61MB
// in R5/R7) + stats precompute (kills R5's 8x softmax replication) + 16-edge
// 1KB load instructions (fixes R7's 256B/instr). Hs slice-major [8][N][16];
// gather writes inv-applied Hagg[d][128] (= row-major per head), consumed
// directly by next gemm's staging (bias+relu fused there). Layer3: tiny pool
// epilogue -> pvn, finalize by binary search.

__device__ __forceinline__ float lrelu(float v) { return v > 0.f ? v : 0.2f * v; }

__device__ __forceinline__ float wave_sum(float v) {
  for (int off = 32; off; off >>= 1) v += __shfl_xor(v, off, 64);
  return v;
}
__device__ __forceinline__ float wave_max(float v) {
  for (int off = 32; off; off >>= 1) v = fmaxf(v, __shfl_xor(v, off, 64));
  return v;
}

__global__ void init_kernel(int* __restrict__ deg, int n) {
  int i = blockIdx.x * blockDim.x + threadIdx.x;
  if (i < n) deg[i] = 1;                 // self loop occupies rank 0
}

// rank[j] = arrival order within dst (1-based; 0 = self loop). 4 indep atomics.
__global__ void count_rank(const int* __restrict__ ei, int* __restrict__ deg,
                           int* __restrict__ rank, int e) {
  int j0 = blockIdx.x * 1024 + threadIdx.x;
#pragma unroll
  for (int k = 0; k < 4; ++k) {
    int j = j0 + k * 256;
    if (j < e) rank[j] = atomicAdd(&deg[ei[e + j]], 1);
  }
}

// ---- hierarchical exclusive scan over deg[0..n) ----
__global__ void scan_blocks(const int* __restrict__ deg, int* __restrict__ row_ptr,
                            int* __restrict__ btot, int n) {
  __shared__ int sm[256];
  int i = blockIdx.x * 256 + threadIdx.x;
  int v = (i < n) ? deg[i] : 0;
  sm[threadIdx.x] = v;
  __syncthreads();
  for (int off = 1; off < 256; off <<= 1) {
    int t = (threadIdx.x >= off) ? sm[threadIdx.x - off] : 0;
    __syncthreads();
    sm[threadIdx.x] += t;
    __syncthreads();
  }
  if (i < n) row_ptr[i] = sm[threadIdx.x] - v;   // exclusive within block
  if (threadIdx.x == 255) btot[blockIdx.x] = sm[255];
}

__global__ void scan_totals(int* __restrict__ btot, int nb) {  // nb <= 256
  __shared__ int sm[256];
  int v = (threadIdx.x < nb) ? btot[threadIdx.x] : 0;
  sm[threadIdx.x] = v;
  __syncthreads();
  for (int off = 1; off < 256; off <<= 1) {
    int t = (threadIdx.x >= off) ? sm[threadIdx.x - off] : 0;
    __syncthreads();
    sm[threadIdx.x] += t;
    __syncthreads();
  }
  if (threadIdx.x < nb) btot[threadIdx.x] = sm[threadIdx.x] - v;  // exclusive
}

// finalize row_ptr + drop self-loop into csr (rank 0)
__global__ void scan_add(int* __restrict__ row_ptr, int* __restrict__ csr,
                         const int* __restrict__ btot, int n, int total) {
  int i = blockIdx.x * 256 + threadIdx.x;
  if (i < n) {
    int v = row_ptr[i] + btot[blockIdx.x];
    row_ptr[i] = v;
    csr[v] = i;                         // self loop
  }
  if (i == 0) row_ptr[n] = total;
}

// no atomics: slot = row_ptr[dst] + rank. 4 independent edges per thread.
__global__ void place_kernel(const int* __restrict__ ei, const int* __restrict__ rank,
                             const int* __restrict__ row_ptr, int* __restrict__ csr,
                             int e) {
  int j0 = blockIdx.x * 1024 + threadIdx.x;
#pragma unroll
  for (int k = 0; k < 4; ++k) {
    int j = j0 + k * 256;
    if (j < e) {
      int d = ei[e + j];
      csr[row_ptr[d] + rank[j]] = ei[j];
    }
  }
}

// Tiled gemm + fused attention reduce. Output SLICE-MAJOR:
// Hs[slice][node][16], slice = col/16 (0-3 head0, 4-7 head1).
// SRC=0: X is plain [N,K]. SRC=1 (K=64): X is Hagg [N,128] (inv-applied);
// staging computes relu(0.5*(h0+h1)+bprev) — the previous layer's epilogue.
template <int K, int SRC>
__global__ __launch_bounds__(256) void gemm_att(const float* __restrict__ X,
                                                const float* __restrict__ Wm,
                                                const float* __restrict__ asw,
                                                const float* __restrict__ adw,
                                                const float* __restrict__ bprev,
                                                float* __restrict__ Hs,
                                                float* __restrict__ a_src,
                                                float* __restrict__ a_dst, int N) {
  __shared__ float Xs[64 * (K + 1)];
  int tid = threadIdx.x;
  int row0 = blockIdx.x * 64;
  int head = blockIdx.y;

  if (SRC == 0) {
    for (int idx = tid; idx < 64 * K; idx += 256) {
      int r = idx / K;
      int k = idx - r * K;
      int gr = row0 + r;
      if (gr >= N) gr = N - 1;          // clamp pad rows (stores are guarded)
      Xs[r * (K + 1) + k] = X[(size_t)gr * K + k];
    }
  } else {
    for (int idx = tid; idx < 64 * 64; idx += 256) {
      int r = idx >> 6;
      int c = idx & 63;
      int gr = row0 + r;
      if (gr >= N) gr = N - 1;
      const float* hp = X + (size_t)gr * 128;
      float v = 0.5f * (hp[c] + hp[64 + c]) + bprev[c];
      Xs[r * (K + 1) + c] = v > 0.f ? v : 0.f;
    }
  }
  __syncthreads();

  int cgrp = tid & 15;
  int rg = tid >> 4;
  int c0 = head * 64 + cgrp * 4;
  const float* wp = Wm + c0;
  float acc[4][4] = {};

#pragma unroll 4
  for (int k = 0; k < K; ++k) {
    float4 w4 = *(const float4*)(wp + k * 128);
#pragma unroll
    for (int j = 0; j < 4; ++j) {
      float xv = Xs[(rg * 4 + j) * (K + 1) + k];
      acc[j][0] = fmaf(xv, w4.x, acc[j][0]);
      acc[j][1] = fmaf(xv, w4.y, acc[j][1]);
      acc[j][2] = fmaf(xv, w4.z, acc[j][2]);
      acc[j][3] = fmaf(xv, w4.w, acc[j][3]);
    }
  }

  int slice = c0 >> 4;
  int w16 = c0 & 15;
  float4 aw = *(const float4*)(asw + c0);
  float4 dw = *(const float4*)(adw + c0);
#pragma unroll
  for (int j = 0; j < 4; ++j) {
    int r = row0 + rg * 4 + j;
    float sp = acc[j][0] * aw.x + acc[j][1] * aw.y + acc[j][2] * aw.z + acc[j][3] * aw.w;
    float dp = acc[j][0] * dw.x + acc[j][1] * dw.y + acc[j][2] * dw.z + acc[j][3] * dw.w;
#pragma unroll
    for (int off = 1; off < 16; off <<= 1) {
      sp += __shfl_xor(sp, off, 64);
      dp += __shfl_xor(dp, off, 64);
    }
    if (r < N) {
      float4 v = make_float4(acc[j][0], acc[j][1], acc[j][2], acc[j][3]);
      *(float4*)(Hs + ((size_t)slice * N + r) * 16 + w16) = v;
      if (cgrp == 0) {
        a_src[r * 2 + head] = sp;
        a_dst[r * 2 + head] = dp;
      }
    }
  }
}

// Wave per dst: exact softmax; writes per-edge unnormalized p0/p1 (coalesced
// SoA) + per-dst 1/s. All random a_src gathers happen here, once. (R7-verified)
__global__ __launch_bounds__(256) void stats_kernel(
    const float* __restrict__ a_src, const float* __restrict__ a_dst,
    const int* __restrict__ row_ptr, const int* __restrict__ csr,
    float* __restrict__ p0a, float* __restrict__ p1a,
    float2* __restrict__ invS, int N) {
  int wid = blockIdx.x * 4 + (threadIdx.x >> 6);
  if (wid >= N) return;
  int lane = threadIdx.x & 63;
  int beg = row_ptr[wid], end = row_ptr[wid + 1];
  float2 ad = ((const float2*)a_dst)[wid];

  if (end - beg <= 64) {
    int j = beg + lane;
    bool valid = j < end;
    int s = valid ? csr[j] : 0;
    float2 as = ((const float2*)a_src)[s];
    float e0 = valid ? lrelu(as.x + ad.x) : -1e30f;
    float e1 = valid ? lrelu(as.y + ad.y) : -1e30f;
    float m0 = wave_max(e0), m1 = wave_max(e1);
    float p0 = __expf(e0 - m0), p1 = __expf(e1 - m1);
    float s0 = wave_sum(valid ? p0 : 0.f);
    float s1 = wave_sum(valid ? p1 : 0.f);
    if (valid) { p0a[j] = p0; p1a[j] = p1; }
    if (lane == 0)
      invS[wid] = make_float2(1.f / fmaxf(s0, 1e-16f), 1.f / fmaxf(s1, 1e-16f));
  } else {
    float m0 = -1e30f, m1 = -1e30f, s0 = 0.f, s1 = 0.f;
    for (int base = beg; base < end; base += 64) {
      int j = base + lane;
      bool valid = j < end;
      int s = valid ? csr[j] : 0;
      float2 as = ((const float2*)a_src)[s];
      float e0 = valid ? lrelu(as.x + ad.x) : -1e30f;
      float e1 = valid ? lrelu(as.y + ad.y) : -1e30f;
      float nm0 = fmaxf(m0, wave_max(e0));
      float nm1 = fmaxf(m1, wave_max(e1));
      s0 = s0 * __expf(m0 - nm0) + wave_sum(valid ? __expf(e0 - nm0) : 0.f);
      s1 = s1 * __expf(m1 - nm1) + wave_sum(valid ? __expf(e1 - nm1) : 0.f);
      m0 = nm0; m1 = nm1;
    }
    for (int base = beg; base < end; base += 64) {
      int j = base + lane;
      bool valid = j < end;
      int s = valid ? csr[j] : 0;
      float2 as = ((const float2*)a_src)[s];
      if (valid) {
        p0a[j] = __expf(lrelu(as.x + ad.x) - m0);
        p1a[j] = __expf(lrelu(as.y + ad.y) - m1);
      }
    }
    if (lane == 0)
      invS[wid] = make_float2(1.f / fmaxf(s0, 1e-16f), 1.f / fmaxf(s1, 1e-16f));
  }
}

// XCD-sliced gather v3. Grid: 8 x ceil(N/4); slice = blockIdx&7 (pins the
// 3.2MB slice to one XCD's L2); wave = one dst. Lane = (t16 = lane>>2,
// c4 = (lane&3)*4). Per 64-edge chunk: coalesced (csr, pH) into lane regs,
// then 4 groups x [2 bpermute + ONE 1KB load instr (16 edges x 64B slices)
// + 4 fma]. Branchless: pad lanes carry s=0, p=0 (row-0 slice = 1 hot line).
// Reduce over t16 (xor 4,8,16,32); lanes 0-3 store inv-applied 64B to Hagg.
__global__ __launch_bounds__(256) void gather_slices3(
    const float* __restrict__ Hs, const int* __restrict__ row_ptr,
    const int* __restrict__ csr, const float* __restrict__ p0a,
    const float* __restrict__ p1a, const float2* __restrict__ invS,
    float* __restrict__ Hagg, int N) {
  int sl = blockIdx.x & 7;
  int dst = (blockIdx.x >> 3) * 4 + (threadIdx.x >> 6);
  if (dst >= N) return;
  int lane = threadIdx.x & 63;
  int t16 = lane >> 2;
  int c4 = (lane & 3) * 4;
  const float* __restrict__ pH = (sl < 4) ? p0a : p1a;
  const float* __restrict__ hsb = Hs + (size_t)sl * N * 16 + c4;
  int beg = row_ptr[dst], end = row_ptr[dst + 1];
  int cnt = end - beg;
  float4 acc = make_float4(0.f, 0.f, 0.f, 0.f);

  for (int base = 0; base < cnt; base += 64) {
    int j = base + lane;
    bool valid = j < cnt;
    int sj = valid ? csr[beg + j] : 0;
    float pj = valid ? pH[beg + j] : 0.f;
    int rem = cnt - base;
    int gmax = (rem >= 49) ? 4 : ((rem + 15) >> 4);   // wave-uniform
    int st[4];
    float q[4];
    float4 h[4];
#pragma unroll
    for (int g = 0; g < 4; ++g) {
      if (g < gmax) {
        int idx = g * 16 + t16;
        st[g] = __shfl(sj, idx, 64);
        q[g] = __shfl(pj, idx, 64);
        h[g] = *(const float4*)(hsb + (size_t)st[g] * 16);
      } else {
        q[g] = 0.f;
        h[g] = make_float4(0.f, 0.f, 0.f, 0.f);
      }
    }
#pragma unroll
    for (int g = 0; g < 4; ++g) {
      acc.x = fmaf(h[g].x, q[g], acc.x);
      acc.y = fmaf(h[g].y, q[g], acc.y);
      acc.z = fmaf(h[g].z, q[g], acc.z);
      acc.w = fmaf(h[g].w, q[g], acc.w);
    }
  }

  // reduce across t16 (lane bits 2-5); c4 (bits 0-1) preserved
#pragma unroll
  for (int off = 4; off <= 32; off <<= 1) {
    acc.x += __shfl_xor(acc.x, off, 64);
    acc.y += __shfl_xor(acc.y, off, 64);
    acc.z += __shfl_xor(acc.z, off, 64);
    acc.w += __shfl_xor(acc.w, off, 64);
  }
  if (t16 == 0) {
    float2 iv = invS[dst];
    float inv = (sl < 4) ? iv.x : iv.y;
    float4 r = make_float4(acc.x * inv, acc.y * inv, acc.z * inv, acc.w * inv);
    *(float4*)(Hagg + (size_t)dst * 128 + sl * 16 + c4) = r;
  }
}

// layer-3 epilogue + pool: wave per dst, lane = col. pv = relu-row . lw.
__global__ void pool_epilogue(const float* __restrict__ Hagg,
                              const float* __restrict__ bias,
                              const float* __restrict__ lw,
                              float* __restrict__ pvn, int N) {
  int d = blockIdx.x * 4 + (threadIdx.x >> 6);
  if (d >= N) return;
  int c = threadIdx.x & 63;
  const float* hp = Hagg + (size_t)d * 128;
  float v = 0.5f * (hp[c] + hp[64 + c]) + bias[c];
  v = v > 0.f ? v : 0.f;
  float pv = wave_sum(v * lw[c]);
  if (c == 0) pvn[d] = pv;
}

__device__ __forceinline__ int lower_bound(const int* __restrict__ a, int n, int key) {
  int lo = 0, hi = n;
  while (lo < hi) {
    int mid = (lo + hi) >> 1;
    if (a[mid] < key) lo = mid + 1; else hi = mid;
  }
  return lo;
}

// per graph: boundaries via binary search in sorted batch, mean of pvn + lb
__global__ void finalize_kernel(const float* __restrict__ pvn,
                                const int* __restrict__ batch,
                                const float* __restrict__ lb,
                                float* __restrict__ out, int N, int G) {
  int g = blockIdx.x * blockDim.x + threadIdx.x;
  if (g >= G) return;
  int lo = lower_bound(batch, N, g);
  int hi = lower_bound(batch, N, g + 1);
  float s = 0.f;
  for (int i = lo; i < hi; ++i) s += pvn[i];
  out[g] = s / fmaxf((float)(hi - lo), 1.f) + lb[0];
}

extern "C" void kernel_launch(void* const* d_in, const int* in_sizes, int n_in,
                              void* d_out, int out_size, void* d_ws, size_t ws_size,
                              hipStream_t stream) {
  const float* x   = (const float*)d_in[0];
  const int* ei    = (const int*)d_in[1];
  const int* batch = (const int*)d_in[2];
  const float* W1  = (const float*)d_in[3];
  const float* as1 = (const float*)d_in[4];
  const float* ad1 = (const float*)d_in[5];
  const float* b1  = (const float*)d_in[6];
  const float* W2  = (const float*)d_in[7];
  const float* as2 = (const float*)d_in[8];
  const float* ad2 = (const float*)d_in[9];
  const float* b2  = (const float*)d_in[10];
  const float* W3  = (const float*)d_in[11];
  const float* as3 = (const float*)d_in[12];
  const float* ad3 = (const float*)d_in[13];
  const float* b3  = (const float*)d_in[14];
  const float* lw  = (const float*)d_in[15];
  const float* lb  = (const float*)d_in[16];
  float* out = (float*)d_out;

  const int N = in_sizes[0] / 128;   // 50000
  const int E = in_sizes[1] / 2;     // 800000
  const int ET = N + E;              // with self loops
  const int G = out_size;            // 2500
  const int NB = (N + 255) / 256;    // scan blocks (196 <= 256)

  char* p = (char*)d_ws;
  auto take = [&](size_t bytes) {
    char* r = p;
    p += (bytes + 255) & ~(size_t)255;
    return r;
  };
  int* deg      = (int*)take((size_t)N * 4);
  int* row_ptr  = (int*)take((size_t)(N + 1) * 4);
  int* rank     = (int*)take((size_t)E * 4);
  int* btot     = (int*)take((size_t)NB * 4);
  int* csr      = (int*)take((size_t)ET * 4);
  float* Hs     = (float*)take((size_t)N * 128 * 4);  // slice-major
  float* Hagg   = (float*)take((size_t)N * 128 * 4);  // row-major per head
  float* a_src  = (float*)take((size_t)N * 2 * 4);
  float* a_dst  = (float*)take((size_t)N * 2 * 4);
  float* p0a    = (float*)take((size_t)ET * 4);
  float* p1a    = (float*)take((size_t)ET * 4);
  float2* invS  = (float2*)take((size_t)N * 8);
  float* pvn    = (float*)take((size_t)N * 4);
  (void)ws_size; (void)n_in;

  // ---- CSR build (dst-grouped, with self loops) ----
  init_kernel<<<(N + 255) / 256, 256, 0, stream>>>(deg, N);
  count_rank<<<(E + 1023) / 1024, 256, 0, stream>>>(ei, deg, rank, E);
  scan_blocks<<<NB, 256, 0, stream>>>(deg, row_ptr, btot, N);
  scan_totals<<<1, 256, 0, stream>>>(btot, NB);
  scan_add<<<NB, 256, 0, stream>>>(row_ptr, csr, btot, N, ET);
  place_kernel<<<(E + 1023) / 1024, 256, 0, stream>>>(ei, rank, row_ptr, csr, E);

  const dim3 gblk((N + 63) / 64, 2);
  const int wblk = (N + 3) / 4;
  const int sblk = 8 * ((N + 3) / 4);

  // ---- layer 1 (K=128, plain X) ----
  gemm_att<128, 0><<<gblk, 256, 0, stream>>>(x, W1, as1, ad1, nullptr,
                                             Hs, a_src, a_dst, N);
  stats_kernel<<<wblk, 256, 0, stream>>>(a_src, a_dst, row_ptr, csr, p0a, p1a, invS, N);
  gather_slices3<<<sblk, 256, 0, stream>>>(Hs, row_ptr, csr, p0a, p1a, invS, Hagg, N);
  // ---- layer 2 (K=64, X = Hagg + b1 epilogue fused in staging) ----
  gemm_att<64, 1><<<gblk, 256, 0, stream>>>(Hagg, W2, as2, ad2, b1,
                                            Hs, a_src, a_dst, N);
  stats_kernel<<<wblk, 256, 0, stream>>>(a_src, a_dst, row_ptr, csr, p0a, p1a, invS, N);
  gather_slices3<<<sblk, 256, 0, stream>>>(Hs, row_ptr, csr, p0a, p1a, invS, Hagg, N);
  // ---- layer 3 (K=64, X = Hagg + b2 epilogue fused) ----
  gemm_att<64, 1><<<gblk, 256, 0, stream>>>(Hagg, W3, as3, ad3, b2,
                                            Hs, a_src, a_dst, N);
  stats_kernel<<<wblk, 256, 0, stream>>>(a_src, a_dst, row_ptr, csr, p0a, p1a, invS, N);
  gather_slices3<<<sblk, 256, 0, stream>>>(Hs, row_ptr, csr, p0a, p1a, invS, Hagg, N);

  // ---- pool (b3 epilogue) + finalize ----
  pool_epilogue<<<wblk, 256, 0, stream>>>(Hagg, b3, lw, pvn, N);
  finalize_kernel<<<(G + 255) / 256, 256, 0, stream>>>(pvn, batch, lb, out, N, G);
}

// Round 13
// 425.377 us; speedup vs baseline: 1.5231x; 1.5231x over previous
//
#include <hip/hip_runtime.h>
#include <math.h>

// GAT 3-layer: N=50000 nodes, E=800000 edges (+N self loops), HEADS=2, HID=64.
// R13 = R11 (best aggregate: 2 dsts/wave float4 gather, fetch-floor-bound at
// ~194MB / 3.3TB/s — slicing disproven 3x) + gemm ds_read_b128 (k-unroll 4,
// row stride K+4 keeps 16B alignment; was 4x ds_read_b32 per k) + CSR build
// without init kernel (memset deg=0; row_ptr = scan(deg)+i reserves self-loop
// slot 0; place at row_ptr[d]+1+rank).

__device__ __forceinline__ float lrelu(float v) { return v > 0.f ? v : 0.2f * v; }

__device__ __forceinline__ float wave_max(float v) {
  for (int off = 32; off; off >>= 1) v = fmaxf(v, __shfl_xor(v, off, 64));
  return v;
}
__device__ __forceinline__ float wave_sum(float v) {
  for (int off = 32; off; off >>= 1) v += __shfl_xor(v, off, 64);
  return v;
}
// 32-lane (half-wave) reductions
__device__ __forceinline__ float half_sum(float v) {
  for (int off = 16; off; off >>= 1) v += __shfl_xor(v, off, 64);
  return v;
}
__device__ __forceinline__ float half_max(float v) {
  for (int off = 16; off; off >>= 1) v = fmaxf(v, __shfl_xor(v, off, 64));
  return v;
}

// rank[j] = 0-based arrival order within dst. 4 indep atomics in flight.
__global__ void count_rank(const int* __restrict__ ei, int* __restrict__ deg,
                           int* __restrict__ rank, int e) {
  int j0 = blockIdx.x * 1024 + threadIdx.x;
#pragma unroll
  for (int k = 0; k < 4; ++k) {
    int j = j0 + k * 256;
    if (j < e) rank[j] = atomicAdd(&deg[ei[e + j]], 1);
  }
}

// ---- hierarchical exclusive scan over deg[0..n) (counts only) ----
__global__ void scan_blocks(const int* __restrict__ deg, int* __restrict__ row_ptr,
                            int* __restrict__ btot, int n) {
  __shared__ int sm[256];
  int i = blockIdx.x * 256 + threadIdx.x;
  int v = (i < n) ? deg[i] : 0;
  sm[threadIdx.x] = v;
  __syncthreads();
  for (int off = 1; off < 256; off <<= 1) {
    int t = (threadIdx.x >= off) ? sm[threadIdx.x - off] : 0;
    __syncthreads();
    sm[threadIdx.x] += t;
    __syncthreads();
  }
  if (i < n) row_ptr[i] = sm[threadIdx.x] - v;   // exclusive within block
  if (threadIdx.x == 255) btot[blockIdx.x] = sm[255];
}

__global__ void scan_totals(int* __restrict__ btot, int nb) {  // nb <= 256
  __shared__ int sm[256];
  int v = (threadIdx.x < nb) ? btot[threadIdx.x] : 0;
  sm[threadIdx.x] = v;
  __syncthreads();
  for (int off = 1; off < 256; off <<= 1) {
    int t = (threadIdx.x >= off) ? sm[threadIdx.x - off] : 0;
    __syncthreads();
    sm[threadIdx.x] += t;
    __syncthreads();
  }
  if (threadIdx.x < nb) btot[threadIdx.x] = sm[threadIdx.x] - v;  // exclusive
}

// row_ptr[i] = scan(counts) + i  (the +i reserves each node's self-loop slot);
// drop self-loop into csr at rank 0.
__global__ void scan_add(int* __restrict__ row_ptr, int* __restrict__ csr,
                         const int* __restrict__ btot, int n, int total) {
  int i = blockIdx.x * 256 + threadIdx.x;
  if (i < n) {
    int v = row_ptr[i] + btot[blockIdx.x] + i;
    row_ptr[i] = v;
    csr[v] = i;                         // self loop
  }
  if (i == 0) row_ptr[n] = total;
}

// no atomics: slot = row_ptr[dst] + 1 + rank. 4 independent edges per thread.
__global__ void place_kernel(const int* __restrict__ ei, const int* __restrict__ rank,
                             const int* __restrict__ row_ptr, int* __restrict__ csr,
                             int e) {
  int j0 = blockIdx.x * 1024 + threadIdx.x;
#pragma unroll
  for (int k = 0; k < 4; ++k) {
    int j = j0 + k * 256;
    if (j < e) {
      int d = ei[e + j];
      csr[row_ptr[d] + 1 + rank[j]] = ei[j];
    }
  }
}

// Tiled gemm + fused attention reduce.
// Block = 64 rows x 64 cols (blockIdx.y = head). 256 threads: cgrp = tid&15
// -> cols head*64 + cgrp*4; rg = tid>>4 -> rows rg*4..+4. 4x4 acc/thread.
// Xs row stride K+4 (16B-aligned rows); k unrolled by 4 so each row's 4
// k-values come from ONE ds_read_b128 (2 addrs/bank across lanes = free).
// W slice Kx64 L1-resident. Att reduce over cgrp via 16-lane shfl_xor.
template <int K>
__global__ __launch_bounds__(256) void gemm_att(const float* __restrict__ X,
                                                const float* __restrict__ W,
                                                const float* __restrict__ asw,
                                                const float* __restrict__ adw,
                                                float* __restrict__ H,
                                                float* __restrict__ a_src,
                                                float* __restrict__ a_dst, int N) {
  __shared__ float Xs[64 * (K + 4)];
  int tid = threadIdx.x;
  int row0 = blockIdx.x * 64;
  int head = blockIdx.y;

  for (int idx = tid; idx < 64 * K; idx += 256) {
    int r = idx / K;
    int k = idx - r * K;
    int gr = row0 + r;
    if (gr >= N) gr = N - 1;          // clamp pad rows (stores are guarded)
    Xs[r * (K + 4) + k] = X[(size_t)gr * K + k];
  }
  __syncthreads();

  int cgrp = tid & 15;
  int rg = tid >> 4;
  int c0 = head * 64 + cgrp * 4;
  const float* wp = W + c0;
  float acc[4][4] = {};

#pragma unroll 2
  for (int k = 0; k < K; k += 4) {
    float4 xr[4];
#pragma unroll
    for (int j = 0; j < 4; ++j)
      xr[j] = *(const float4*)(&Xs[(rg * 4 + j) * (K + 4) + k]);
#pragma unroll
    for (int kk = 0; kk < 4; ++kk) {
      float4 w4 = *(const float4*)(wp + (k + kk) * 128);
#pragma unroll
      for (int j = 0; j < 4; ++j) {
        float xv = ((const float*)&xr[j])[kk];
        acc[j][0] = fmaf(xv, w4.x, acc[j][0]);
        acc[j][1] = fmaf(xv, w4.y, acc[j][1]);
        acc[j][2] = fmaf(xv, w4.z, acc[j][2]);
        acc[j][3] = fmaf(xv, w4.w, acc[j][3]);
      }
    }
  }

  float4 aw = *(const float4*)(asw + c0);
  float4 dw = *(const float4*)(adw + c0);
#pragma unroll
  for (int j = 0; j < 4; ++j) {
    int r = row0 + rg * 4 + j;
    float sp = acc[j][0] * aw.x + acc[j][1] * aw.y + acc[j][2] * aw.z + acc[j][3] * aw.w;
    float dp = acc[j][0] * dw.x + acc[j][1] * dw.y + acc[j][2] * dw.z + acc[j][3] * dw.w;
#pragma unroll
    for (int off = 1; off < 16; off <<= 1) {
      sp += __shfl_xor(sp, off, 64);
      dp += __shfl_xor(dp, off, 64);
    }
    if (r < N) {
      float4 v = make_float4(acc[j][0], acc[j][1], acc[j][2], acc[j][3]);
      *(float4*)(H + (size_t)r * 128 + c0) = v;
      if (cgrp == 0) {
        a_src[r * 2 + head] = sp;
        a_dst[r * 2 + head] = dp;
      }
    }
  }
}

// ---- float4 pipelined gather: 8 loads (1KB each) in flight per wave ----
__device__ __forceinline__ void ld_grp4(const float* __restrict__ H, int half,
                                        int col4, int headsel, int s, float p0,
                                        float p1, int g, float4* h, float* q) {
#pragma unroll
  for (int k = 0; k < 8; ++k) {
    int idx = half + g * 8 + k;          // within own half (g*8+k <= 31)
    int st = __shfl(s, idx, 64);
    float q0 = __shfl(p0, idx, 64);
    float q1 = __shfl(p1, idx, 64);
    q[k] = headsel ? q1 : q0;
    h[k] = *(const float4*)(H + (size_t)st * 128 + col4);
  }
}
__device__ __forceinline__ void fma_grp4(const float4* h, const float* q,
                                         float4& a) {
#pragma unroll
  for (int k = 0; k < 8; ++k) {
    a.x = fmaf(h[k].x, q[k], a.x);
    a.y = fmaf(h[k].y, q[k], a.y);
    a.z = fmaf(h[k].z, q[k], a.z);
    a.w = fmaf(h[k].w, q[k], a.w);
  }
}
__device__ __forceinline__ void gather_pipe4(const float* __restrict__ H, int half,
                                             int col4, int headsel, int s, float p0,
                                             float p1, int maxcnt, float4& a) {
  int groups = (maxcnt + 7) >> 3;   // 1..4 (chunk of 32)
  float4 ha[8], hb[8];
  float qa[8], qb[8];
  ld_grp4(H, half, col4, headsel, s, p0, p1, 0, ha, qa);
  int g = 1;
  for (; g + 1 < groups; g += 2) {
    ld_grp4(H, half, col4, headsel, s, p0, p1, g, hb, qb);
    fma_grp4(ha, qa, a);
    ld_grp4(H, half, col4, headsel, s, p0, p1, g + 1, ha, qa);
    fma_grp4(hb, qb, a);
  }
  if (g < groups) {
    ld_grp4(H, half, col4, headsel, s, p0, p1, g, hb, qb);
    fma_grp4(ha, qa, a);
    fma_grp4(hb, qb, a);
  } else {
    fma_grp4(ha, qa, a);
  }
}

// Fused softmax + aggregate. 2 dsts per wave: lanes 0-31 -> dst A, 32-63 ->
// dst B. Lane l covers H cols (l&31)*4..+4 (lanes 0-15 of half = head0 cols,
// 16-31 = head1). Softmax per half (32-lane reduce). POOL=1: per-node pv
// plain store into pvn (no atomics).
template <int POOL>
__global__ __launch_bounds__(256) void aggregate_fused(
    const float* __restrict__ H, const float* __restrict__ a_src,
    const float* __restrict__ a_dst, const float* __restrict__ bias,
    const int* __restrict__ row_ptr, const int* __restrict__ csr,
    float* __restrict__ out, const float* __restrict__ lw,
    float* __restrict__ pvn, int N) {
  int lane = threadIdx.x & 63;
  int half = lane & 32;                 // 0 or 32
  int l32 = lane & 31;
  int dst = blockIdx.x * 8 + ((threadIdx.x >> 6) << 1) + (half >> 5);
  bool live = dst < N;
  int beg = live ? row_ptr[dst] : 0;
  int end = live ? row_ptr[dst + 1] : 0;
  int cnt = end - beg;                  // >= 1 when live (self loop)
  float2 ad = live ? ((const float2*)a_dst)[dst] : make_float2(0.f, 0.f);
  int col4 = l32 * 4;
  int headsel = (l32 >> 4) & 1;         // 0: cols 0-63, 1: cols 64-127
  float4 acc = make_float4(0.f, 0.f, 0.f, 0.f);
  float inv0, inv1;

  // wave-uniform max degree (drives loop counts)
  int maxcnt = (int)wave_max((float)cnt);

  if (maxcnt <= 32) {
    // ---- fast path: single 32-chunk per half ----
    int j = beg + l32;
    bool valid = l32 < cnt;
    int s = valid ? csr[j] : 0;
    float2 as = ((const float2*)a_src)[s];
    float e0 = valid ? lrelu(as.x + ad.x) : -1e30f;
    float e1 = valid ? lrelu(as.y + ad.y) : -1e30f;
    float m0 = half_max(e0);
    float m1 = half_max(e1);
    float p0 = __expf(e0 - m0);         // 0 for invalid lanes
    float p1 = __expf(e1 - m1);
    inv0 = 1.f / fmaxf(half_sum(valid ? p0 : 0.f), 1e-16f);
    inv1 = 1.f / fmaxf(half_sum(valid ? p1 : 0.f), 1e-16f);
    gather_pipe4(H, half, col4, headsel, s, p0, p1, maxcnt, acc);
  } else {
    // ---- generic path: online softmax over 32-edge chunks per half ----
    float m0 = -1e30f, m1 = -1e30f, s0 = 0.f, s1 = 0.f;
    for (int base = 0; base < maxcnt; base += 32) {
      int j = beg + base + l32;
      bool valid = (base + l32) < cnt;
      int s = valid ? csr[j] : 0;
      float2 as = ((const float2*)a_src)[s];
      float e0 = valid ? lrelu(as.x + ad.x) : -1e30f;
      float e1 = valid ? lrelu(as.y + ad.y) : -1e30f;
      float nm0 = fmaxf(m0, half_max(e0));
      float nm1 = fmaxf(m1, half_max(e1));
      s0 = s0 * __expf(m0 - nm0) + half_sum(valid ? __expf(e0 - nm0) : 0.f);
      s1 = s1 * __expf(m1 - nm1) + half_sum(valid ? __expf(e1 - nm1) : 0.f);
      m0 = nm0; m1 = nm1;
    }
    inv0 = 1.f / fmaxf(s0, 1e-16f);
    inv1 = 1.f / fmaxf(s1, 1e-16f);
    for (int base = 0; base < maxcnt; base += 32) {
      int j = beg + base + l32;
      bool valid = (base + l32) < cnt;
      int s = valid ? csr[j] : 0;
      float2 as = ((const float2*)a_src)[s];
      float e0 = valid ? lrelu(as.x + ad.x) : -1e30f;
      float e1 = valid ? lrelu(as.y + ad.y) : -1e30f;
      float p0 = __expf(e0 - m0);       // 0 invalid
      float p1 = __expf(e1 - m1);
      int rem = maxcnt - base;
      if (rem > 32) rem = 32;
      gather_pipe4(H, half, col4, headsel, s, p0, p1, rem, acc);
    }
  }

  // epilogue: per-lane inv (own head), head-mean via xor16, bias, relu
  float il = headsel ? inv1 : inv0;
  float4 v = make_float4(acc.x * il, acc.y * il, acc.z * il, acc.w * il);
  float4 w;
  w.x = __shfl_xor(v.x, 16, 64);
  w.y = __shfl_xor(v.y, 16, 64);
  w.z = __shfl_xor(v.z, 16, 64);
  w.w = __shfl_xor(v.w, 16, 64);
  if (headsel == 0 && live) {
    int c = (l32 & 15) * 4;
    float4 b4 = *(const float4*)(bias + c);
    float4 r;
    r.x = fmaxf(0.5f * (v.x + w.x) + b4.x, 0.f);
    r.y = fmaxf(0.5f * (v.y + w.y) + b4.y, 0.f);
    r.z = fmaxf(0.5f * (v.z + w.z) + b4.z, 0.f);
    r.w = fmaxf(0.5f * (v.w + w.w) + b4.w, 0.f);
    if (POOL) {
      float4 l4 = *(const float4*)(lw + c);
      float pv = r.x * l4.x + r.y * l4.y + r.z * l4.z + r.w * l4.w;
      pv += __shfl_xor(pv, 1, 64);
      pv += __shfl_xor(pv, 2, 64);
      pv += __shfl_xor(pv, 4, 64);
      pv += __shfl_xor(pv, 8, 64);
      if ((l32 & 15) == 0) pvn[dst] = pv;
    } else {
      *(float4*)(out + (size_t)dst * 64 + c) = r;
    }
  }
}

__device__ __forceinline__ int lower_bound(const int* __restrict__ a, int n, int key) {
  int lo = 0, hi = n;
  while (lo < hi) {
    int mid = (lo + hi) >> 1;
    if (a[mid] < key) lo = mid + 1; else hi = mid;
  }
  return lo;
}

// per graph: boundaries via binary search in sorted batch, mean of pvn + lb
__global__ void finalize_kernel(const float* __restrict__ pvn,
                                const int* __restrict__ batch,
                                const float* __restrict__ lb,
                                float* __restrict__ out, int N, int G) {
  int g = blockIdx.x * blockDim.x + threadIdx.x;
  if (g >= G) return;
  int lo = lower_bound(batch, N, g);
  int hi = lower_bound(batch, N, g + 1);
  float s = 0.f;
  for (int i = lo; i < hi; ++i) s += pvn[i];
  out[g] = s / fmaxf((float)(hi - lo), 1.f) + lb[0];
}

extern "C" void kernel_launch(void* const* d_in, const int* in_sizes, int n_in,
                              void* d_out, int out_size, void* d_ws, size_t ws_size,
                              hipStream_t stream) {
  const float* x   = (const float*)d_in[0];
  const int* ei    = (const int*)d_in[1];
  const int* batch = (const int*)d_in[2];
  const float* W1  = (const float*)d_in[3];
  const float* as1 = (const float*)d_in[4];
  const float* ad1 = (const float*)d_in[5];
  const float* b1  = (const float*)d_in[6];
  const float* W2  = (const float*)d_in[7];
  const float* as2 = (const float*)d_in[8];
  const float* ad2 = (const float*)d_in[9];
  const float* b2  = (const float*)d_in[10];
  const float* W3  = (const float*)d_in[11];
  const float* as3 = (const float*)d_in[12];
  const float* ad3 = (const float*)d_in[13];
  const float* b3  = (const float*)d_in[14];
  const float* lw  = (const float*)d_in[15];
  const float* lb  = (const float*)d_in[16];
  float* out = (float*)d_out;

  const int N = in_sizes[0] / 128;   // 50000
  const int E = in_sizes[1] / 2;     // 800000
  const int ET = N + E;              // with self loops
  const int G = out_size;            // 2500
  const int NB = (N + 255) / 256;    // scan blocks (196 <= 256)

  char* p = (char*)d_ws;
  auto take = [&](size_t bytes) {
    char* r = p;
    p += (bytes + 255) & ~(size_t)255;
    return r;
  };
  int* deg      = (int*)take((size_t)N * 4);
  int* row_ptr  = (int*)take((size_t)(N + 1) * 4);
  int* rank     = (int*)take((size_t)E * 4);
  int* btot     = (int*)take((size_t)NB * 4);
  int* csr      = (int*)take((size_t)ET * 4);
  float* H      = (float*)take((size_t)N * 128 * 4);
  float* a_src  = (float*)take((size_t)N * 2 * 4);
  float* a_dst  = (float*)take((size_t)N * 2 * 4);
  float* bufA   = (float*)take((size_t)N * 64 * 4);
  float* bufB   = (float*)take((size_t)N * 64 * 4);
  float* pvn    = (float*)take((size_t)N * 4);
  (void)ws_size; (void)n_in;

  // ---- CSR build (dst-grouped, with self loops) ----
  hipMemsetAsync(deg, 0, (size_t)N * 4, stream);
  count_rank<<<(E + 1023) / 1024, 256, 0, stream>>>(ei, deg, rank, E);
  scan_blocks<<<NB, 256, 0, stream>>>(deg, row_ptr, btot, N);
  scan_totals<<<1, 256, 0, stream>>>(btot, NB);
  scan_add<<<NB, 256, 0, stream>>>(row_ptr, csr, btot, N, ET);
  place_kernel<<<(E + 1023) / 1024, 256, 0, stream>>>(ei, rank, row_ptr, csr, E);

  const dim3 gblk((N + 63) / 64, 2);
  const int ablk = (N + 7) / 8;   // 8 dsts per block (2 per wave)

  // ---- layer 1 (K=128) ----
  gemm_att<128><<<gblk, 256, 0, stream>>>(x, W1, as1, ad1, H, a_src, a_dst, N);
  aggregate_fused<0><<<ablk, 256, 0, stream>>>(H, a_src, a_dst, b1, row_ptr, csr,
                                               bufA, lw, pvn, N);
  // ---- layer 2 (K=64) ----
  gemm_att<64><<<gblk, 256, 0, stream>>>(bufA, W2, as2, ad2, H, a_src, a_dst, N);
  aggregate_fused<0><<<ablk, 256, 0, stream>>>(H, a_src, a_dst, b2, row_ptr, csr,
                                               bufB, lw, pvn, N);
  // ---- layer 3 (K=64) + fused pool ----
  gemm_att<64><<<gblk, 256, 0, stream>>>(bufB, W3, as3, ad3, H, a_src, a_dst, N);
  aggregate_fused<1><<<ablk, 256, 0, stream>>>(H, a_src, a_dst, b3, row_ptr, csr,
                                               bufA, lw, pvn, N);

  // ---- finalize: per-graph mean + linear ----
  finalize_kernel<<<(G + 255) / 256, 256, 0, stream>>>(pvn, batch, lb, out, N, G);
}